// Round 5
// baseline (140.912 us; speedup 1.0000x reference)
//
#include <hip/hip_runtime.h>

typedef _Float16 half8 __attribute__((ext_vector_type(8)));
typedef float f32x4 __attribute__((ext_vector_type(4)));

// ---- problem constants ----
constexpr int S    = 2048;
constexpr int DMO  = 512;
constexpr int NHD  = 8;
constexpr int DH   = 64;
constexpr int BB   = 2;
constexpr int RRROWS = 64 + S + 64;   // 2176: 64 pad rows each side

// ---- workspace layout (in _Float16 elements) ----
constexpr size_t OFF_W  = 0;                                   // 5 * 512*512 (Wq,Wk,Wv,Wr,fcw as f16)
constexpr size_t OFF_QU = OFF_W  + (size_t)5*512*512;
constexpr size_t OFF_QV = OFF_QU + (size_t)BB*NHD*S*DH;
constexpr size_t OFF_K  = OFF_QV + (size_t)BB*NHD*S*DH;
constexpr size_t OFF_V  = OFF_K  + (size_t)BB*NHD*S*DH;
constexpr size_t OFF_VT = OFF_V  + (size_t)BB*NHD*S*DH;
constexpr size_t OFF_RR = OFF_VT + (size_t)BB*NHD*S*DH;
constexpr size_t OFF_AV = OFF_RR + (size_t)NHD*RRROWS*DH;
// Phase-based region reuse (each region is 2,097,152 halves = 16bh*2048*64):
//   attention phase:  OFF_V  -> PO[sp=0][bh][row][64]   (V dead after k_vt)
//                     OFF_AV -> PO[sp=1][bh][row][64]
//                     OFF_W[0:262144] (dead Wq f16) -> ML floats m[2][16][2048], l[2][16][2048]
//   fc: combine fused into A-staging (reads PO0/PO1/ML directly)
// NOTE: Qu/Qv are stored PRE-SCALED by 0.125 (folded softmax scale).

static __device__ __forceinline__ f32x4 mfma16(half8 a, half8 b, f32x4 c) {
  return __builtin_amdgcn_mfma_f32_16x16x32_f16(a, b, c, 0, 0, 0);
}

// ---------------------------------------------------------------------------
// k_convert: weights f32->f16 into ws; zero the RRrev pad rows.
// ---------------------------------------------------------------------------
__global__ __launch_bounds__(256) void k_convert(
    const float* __restrict__ Wq, const float* __restrict__ Wk,
    const float* __restrict__ Wv, const float* __restrict__ Wr,
    const float* __restrict__ fcw, _Float16* __restrict__ ws)
{
  const int idx = blockIdx.x * 256 + threadIdx.x;
  constexpr int WTOT = 5 * 512 * 512 / 4;      // 327680 float4 quads
  if (idx < WTOT) {
    const int i4  = idx * 4;
    const int w   = i4 >> 18;                  // which matrix (512*512 = 2^18)
    const int off = i4 & (512 * 512 - 1);
    const float* src = (w == 0) ? Wq : (w == 1) ? Wk : (w == 2) ? Wv : (w == 3) ? Wr : fcw;
    const float4 v = *(const float4*)(src + off);
    _Float16* dst = ws + OFF_W + (size_t)w * 512 * 512 + off;
    dst[0] = (_Float16)v.x; dst[1] = (_Float16)v.y;
    dst[2] = (_Float16)v.z; dst[3] = (_Float16)v.w;
  } else {
    const int p = idx - WTOT;                  // pad-zeroing of RRrev
    if (p < NHD * 128 * DH / 4) {
      const int e   = p * 4;
      const int h   = e >> 13;                 // 128*64 = 8192 per head
      const int rem = e & 8191;
      const int rr  = rem >> 6;                // 0..127
      const int col = rem & 63;
      const int row = (rr < 64) ? rr : (2048 + rr);   // rows [0,64) and [2112,2176)
      _Float16* dst = ws + OFF_RR + ((size_t)h * RRROWS + row) * DH + col;
      dst[0] = (_Float16)0.f; dst[1] = (_Float16)0.f;
      dst[2] = (_Float16)0.f; dst[3] = (_Float16)0.f;
    }
  }
}

// ---------------------------------------------------------------------------
// k_proj: C[m][n] = sum_k A[m][k] * W[n][k]; 128x128 tile, BK=64, 4 waves 2x2.
// z selects op: 0=Q(->Qu,Qv (val+rel)*0.125), 1=K, 2=V, 3=R(->RRrev reversed).
// Epilogue: acc -> LDS 128x140 f16 tile (aliases As/Bs) -> coalesced half8.
// ---------------------------------------------------------------------------
__global__ __launch_bounds__(256, 2) void k_proj(
    const float* __restrict__ q_in, const float* __restrict__ k_in,
    const float* __restrict__ v_in, const float* __restrict__ rel_r,
    const float* __restrict__ rel_u, const float* __restrict__ rel_v,
    _Float16* __restrict__ ws)
{
  __shared__ _Float16 SM[128 * 72 * 2];        // As | Bs; epilogue: Cs 128x140
  _Float16* As = SM;
  _Float16* Bs = SM + 128 * 72;
  const int op = blockIdx.z;
  const int M  = (op == 3) ? 2048 : 4096;
  const int m0 = blockIdx.x * 128, n0 = blockIdx.y * 128;
  if (m0 >= M) return;
  const float*    Ap = (op == 0) ? q_in : (op == 1) ? k_in : (op == 2) ? v_in : rel_r;
  const _Float16* Bw = ws + OFF_W + (size_t)op * 512 * 512;

  const int tid  = threadIdx.x;
  const int lane = tid & 63, wv = tid >> 6;
  const int wm = wv >> 1, wn = wv & 1;
  const int lr = lane >> 4, lc = lane & 15;
  const int srow = tid >> 1, sk = (tid & 1) * 32;

  f32x4 acc[4][4];
#pragma unroll
  for (int i = 0; i < 4; ++i)
#pragma unroll
    for (int j = 0; j < 4; ++j) acc[i][j] = {0.f, 0.f, 0.f, 0.f};

  for (int kt = 0; kt < 8; ++kt) {
    const int k0 = kt * 64;
    { // stage A (f32 -> f16)
      const float* src = Ap + (size_t)(m0 + srow) * 512 + k0 + sk;
      _Float16* d = As + srow * 72 + sk;
#pragma unroll
      for (int q = 0; q < 4; ++q) {
        const float4 a = ((const float4*)src)[2 * q];
        const float4 b = ((const float4*)src)[2 * q + 1];
        half8 h;
        h[0] = (_Float16)a.x; h[1] = (_Float16)a.y; h[2] = (_Float16)a.z; h[3] = (_Float16)a.w;
        h[4] = (_Float16)b.x; h[5] = (_Float16)b.y; h[6] = (_Float16)b.z; h[7] = (_Float16)b.w;
        *(half8*)(d + q * 8) = h;
      }
    }
    { // stage B (f16 weights)
      const _Float16* src = Bw + (size_t)(n0 + srow) * 512 + k0 + sk;
      _Float16* d = Bs + srow * 72 + sk;
#pragma unroll
      for (int q = 0; q < 4; ++q) *(half8*)(d + q * 8) = *(const half8*)(src + q * 8);
    }
    __syncthreads();
#pragma unroll
    for (int ks = 0; ks < 2; ++ks) {
      half8 a[4], b[4];
#pragma unroll
      for (int f = 0; f < 4; ++f)
        a[f] = *(const half8*)(As + (wm * 64 + f * 16 + lc) * 72 + ks * 32 + lr * 8);
#pragma unroll
      for (int f = 0; f < 4; ++f)
        b[f] = *(const half8*)(Bs + (wn * 64 + f * 16 + lc) * 72 + ks * 32 + lr * 8);
#pragma unroll
      for (int fm = 0; fm < 4; ++fm)
#pragma unroll
        for (int fn = 0; fn < 4; ++fn)
          acc[fm][fn] = mfma16(a[fm], b[fn], acc[fm][fn]);
    }
    __syncthreads();
  }

  // ---- epilogue: acc -> Cs (stride 140: lr-group banks {0,24,16,8}) ----
  _Float16* Cs = SM;
#pragma unroll
  for (int fm = 0; fm < 4; ++fm)
#pragma unroll
    for (int fn = 0; fn < 4; ++fn)
#pragma unroll
      for (int r = 0; r < 4; ++r)
        Cs[(wm * 64 + fm * 16 + lr * 4 + r) * 140 + wn * 64 + fn * 16 + lc] =
            (_Float16)acc[fm][fn][r];
  __syncthreads();

  const int row = tid >> 1;            // 0..127
  const int ch  = (tid & 1) * 64;      // 64-col half (head-aligned)
  const int m   = m0 + row;
  const int hh  = (n0 + ch) >> 6;
  if (op == 0) {
    const int b = m >> 11, s = m & 2047;
    const size_t base = ((size_t)(b * NHD + hh) * S + s) * DH;
#pragma unroll
    for (int q = 0; q < 8; ++q) {
      const half8 cv = *(const half8*)(Cs + row * 140 + ch + q * 8);
      half8 ou, ov;
#pragma unroll
      for (int i = 0; i < 8; ++i) {
        const int n = n0 + ch + q * 8 + i;
        const float v = (float)cv[i];
        ou[i] = (_Float16)((v + rel_u[n]) * 0.125f);
        ov[i] = (_Float16)((v + rel_v[n]) * 0.125f);
      }
      *(half8*)(ws + OFF_QU + base + q * 8) = ou;
      *(half8*)(ws + OFF_QV + base + q * 8) = ov;
    }
  } else if (op == 1 || op == 2) {
    const int b = m >> 11, s = m & 2047;
    _Float16* dst = ws + (op == 1 ? OFF_K : OFF_V) +
                    ((size_t)(b * NHD + hh) * S + s) * DH;
#pragma unroll
    for (int q = 0; q < 8; ++q)
      *(half8*)(dst + q * 8) = *(const half8*)(Cs + row * 140 + ch + q * 8);
  } else {
    const int rr = 2111 - m;            // RRrev[64 + (2047 - m)]
    _Float16* dst = ws + OFF_RR + ((size_t)hh * RRROWS + rr) * DH;
#pragma unroll
    for (int q = 0; q < 8; ++q)
      *(half8*)(dst + q * 8) = *(const half8*)(Cs + row * 140 + ch + q * 8);
  }
}

// ---------------------------------------------------------------------------
// k_vt: V[b,h,s,d] -> VT[b,h,d,s] via 64x64 LDS tile. (V region then dead.)
// ---------------------------------------------------------------------------
__global__ __launch_bounds__(256) void k_vt(_Float16* __restrict__ ws)
{
  __shared__ _Float16 t[64 * 72];
  const int bh = blockIdx.x >> 5, st = blockIdx.x & 31;
  const _Float16* V = ws + OFF_V + ((size_t)bh * S + st * 64) * DH;
  const int tid = threadIdx.x;
#pragma unroll
  for (int q = 0; q < 2; ++q) {
    const int c = tid + q * 256;               // 512 chunks of 8 halves
    *(half8*)(t + (c >> 3) * 72 + (c & 7) * 8) = *(const half8*)(V + c * 8);
  }
  __syncthreads();
  _Float16* VT = ws + OFF_VT + (size_t)bh * DH * S + st * 64;
#pragma unroll
  for (int q = 0; q < 2; ++q) {
    const int c = tid + q * 256;
    const int d = c >> 3, sp = (c & 7) * 8;
    half8 h;
#pragma unroll
    for (int i = 0; i < 8; ++i) h[i] = t[(sp + i) * 72 + d];
    *(half8*)(VT + (size_t)d * S + sp) = h;
  }
}

// ---------------------------------------------------------------------------
// k_attn: split-j flash attention, 4 blocks/CU (LDS 38.0KB).
// 1024 blocks: qt=31-(bid>>5) heavy-first, bh=bid&15, sp=(bid>>4)&1.
// V fragments read DIRECTLY from VT (L2-resident) into registers -- no Vs LDS.
// Ds: per-wave 80-col band [64][88]; Ps aliased into same buffer.
// Deferred softmax sum + defer-max THR=8. Qu/Qv pre-scaled by 0.125.
// ---------------------------------------------------------------------------
__global__ __launch_bounds__(256, 4) void k_attn(_Float16* __restrict__ ws)
{
  __shared__ _Float16 Ks[64 * 72];
  __shared__ _Float16 Rs[128 * 72];
  __shared__ _Float16 DsPs[64 * 88];           // Ds band + Ps (time-aliased)

  const int bid = blockIdx.x;
  const int qi  = bid >> 5;
  const int qt  = 31 - qi;                     // heavy tiles dispatched first
  const int bh  = bid & 15;
  const int sp  = (bid >> 4) & 1;
  const int i0  = qt * 64;
  const int h   = bh & 7;

  const int nt = qt + 1;                       // j-tiles in causal range
  const int nh = (nt + 1) >> 1;
  const int jb = sp ? nh : 0;
  const int je = sp ? nt : nh;

  const _Float16* Qu = ws + OFF_QU + (size_t)bh * S * DH;
  const _Float16* Qv = ws + OFF_QV + (size_t)bh * S * DH;
  const _Float16* Kg = ws + OFF_K  + (size_t)bh * S * DH;
  const _Float16* VTg = ws + OFF_VT + (size_t)bh * DH * S;
  const _Float16* RR = ws + OFF_RR + (size_t)h * RRROWS * DH;
  _Float16* PO = ws + (sp ? OFF_AV : OFF_V);   // [bh][row][64] per split
  float*    ML = (float*)ws;                   // m: [sp][bh][2048]; l at +65536

  const int tid = threadIdx.x, lane = tid & 63, wv = tid >> 6;
  const int lr = lane >> 4, lc = lane & 15;

  half8 qu[2], qv[2];
  {
    const size_t ro = (size_t)(i0 + wv * 16 + lc) * DH + lr * 8;
    qu[0] = *(const half8*)(Qu + ro); qu[1] = *(const half8*)(Qu + ro + 32);
    qv[0] = *(const half8*)(Qv + ro); qv[1] = *(const half8*)(Qv + ro + 32);
  }

  f32x4 oacc[4];
#pragma unroll
  for (int i = 0; i < 4; ++i) oacc[i] = {0.f, 0.f, 0.f, 0.f};
  float mrow[4] = {-1e30f, -1e30f, -1e30f, -1e30f};
  float lrow[4] = {0.f, 0.f, 0.f, 0.f};        // per-lane partial sums

  for (int jt = jb; jt < je; ++jt) {
    const int j0 = jt * 64;

    // ---- V fragments: direct global gathers (L2-resident), hide under MFMA
    half8 vf[2][4];
#pragma unroll
    for (int ks = 0; ks < 2; ++ks)
#pragma unroll
      for (int nf = 0; nf < 4; ++nf)
        vf[ks][nf] = *(const half8*)(VTg + (size_t)(nf * 16 + lc) * S + j0 + ks * 32 + lr * 8);

    // ---- stage K tile + RR window ----
    {
      const _Float16* src = Kg + (size_t)j0 * DH;
#pragma unroll
      for (int q = 0; q < 2; ++q) {
        const int c = tid + q * 256;
        *(half8*)(Ks + (c >> 3) * 72 + (c & 7) * 8) = *(const half8*)(src + c * 8);
      }
      const int r0 = i0 - j0 + 1;
#pragma unroll
      for (int q = 0; q < 4; ++q) {
        const int c = tid + q * 256;
        const int row = c >> 3, cp = (c & 7) * 8;
        *(half8*)(Rs + row * 72 + cp) = *(const half8*)(RR + (size_t)(r0 + row) * DH + cp);
      }
    }
    __syncthreads();

    // ---- D band = Qv @ RRwin^T, cols [wv*16, wv*16+80) -> band store ----
    {
      f32x4 dacc[5];
#pragma unroll
      for (int i = 0; i < 5; ++i) dacc[i] = {0.f, 0.f, 0.f, 0.f};
#pragma unroll
      for (int cf = 0; cf < 5; ++cf)
#pragma unroll
        for (int ks = 0; ks < 2; ++ks) {
          const half8 rb = *(const half8*)(Rs + ((wv + cf) * 16 + lc) * 72 + ks * 32 + lr * 8);
          dacc[cf] = mfma16(qv[ks], rb, dacc[cf]);
        }
#pragma unroll
      for (int cf = 0; cf < 5; ++cf)
#pragma unroll
        for (int r = 0; r < 4; ++r)
          DsPs[(wv * 16 + lr * 4 + r) * 88 + cf * 16 + lc] = (_Float16)dacc[cf][r];
    }

    // ---- AC = Qu @ K^T ----
    f32x4 sacc[4];
#pragma unroll
    for (int i = 0; i < 4; ++i) sacc[i] = {0.f, 0.f, 0.f, 0.f};
#pragma unroll
    for (int jf = 0; jf < 4; ++jf)
#pragma unroll
      for (int ks = 0; ks < 2; ++ks) {
        const half8 kb = *(const half8*)(Ks + (jf * 16 + lc) * 72 + ks * 32 + lr * 8);
        sacc[jf] = mfma16(qu[ks], kb, sacc[jf]);
      }

    // ---- scores (band-read D; already scaled) + online softmax ----
    const bool diag = (j0 == i0);
    float sv[4][4];
    float rmax[4] = {-1e30f, -1e30f, -1e30f, -1e30f};
#pragma unroll
    for (int jf = 0; jf < 4; ++jf)
#pragma unroll
      for (int r = 0; r < 4; ++r) {
        const int rr4 = lr * 4 + r;            // row within wave slice
        const int ii  = wv * 16 + rr4;
        const int jj  = jf * 16 + lc;
        float x = sacc[jf][r] + (float)DsPs[ii * 88 + rr4 + 63 - jj];
        if (diag && (jj > ii)) x = -1e30f;     // causal mask, diag tile only
        sv[jf][r] = x;
        rmax[r] = fmaxf(rmax[r], x);
      }
#pragma unroll
    for (int r = 0; r < 4; ++r)
#pragma unroll
      for (int d = 1; d < 16; d <<= 1)
        rmax[r] = fmaxf(rmax[r], __shfl_xor(rmax[r], d));

    // defer-max: only rescale when max grew by > 8
    bool ok = true;
#pragma unroll
    for (int r = 0; r < 4; ++r) ok = ok && (rmax[r] <= mrow[r] + 8.f);
    if (!__all((int)ok)) {
#pragma unroll
      for (int r = 0; r < 4; ++r) {
        const float mn = fmaxf(mrow[r], rmax[r]);
        const float al = __expf(mrow[r] - mn);
        mrow[r] = mn;
        lrow[r] *= al;
#pragma unroll
        for (int nf = 0; nf < 4; ++nf) oacc[nf][r] *= al;
      }
    }

    // ---- P = exp(S - m); per-lane partial sums; store to Ps (aliased) ----
#pragma unroll
    for (int jf = 0; jf < 4; ++jf)
#pragma unroll
      for (int r = 0; r < 4; ++r) {
        const int ii = wv * 16 + lr * 4 + r;
        const int jj = jf * 16 + lc;
        const float p = __expf(sv[jf][r] - mrow[r]);
        lrow[r] += p;
        DsPs[ii * 88 + jj] = (_Float16)p;
      }

    // ---- O += P @ V (V from registers) ----
#pragma unroll
    for (int ks = 0; ks < 2; ++ks) {
      const half8 pa = *(const half8*)(DsPs + (wv * 16 + lc) * 88 + ks * 32 + lr * 8);
#pragma unroll
      for (int nf = 0; nf < 4; ++nf)
        oacc[nf] = mfma16(pa, vf[ks][nf], oacc[nf]);
    }
    __syncthreads();
  }

  // ---- epilogue: reduce lrow, write unnormalized partials ----
#pragma unroll
  for (int r = 0; r < 4; ++r)
#pragma unroll
    for (int d = 1; d < 16; d <<= 1)
      lrow[r] += __shfl_xor(lrow[r], d);

#pragma unroll
  for (int nf = 0; nf < 4; ++nf)
#pragma unroll
    for (int r = 0; r < 4; ++r) {
      const int row = i0 + wv * 16 + lr * 4 + r;
      PO[((size_t)bh * S + row) * DH + nf * 16 + lc] = (_Float16)oacc[nf][r];
    }
  if (lc == 0) {
#pragma unroll
    for (int r = 0; r < 4; ++r) {
      const int row = i0 + wv * 16 + lr * 4 + r;
      const int idx = (sp * 16 + bh) * S + row;
      ML[idx]         = mrow[r];
      ML[65536 + idx] = lrow[r];
    }
  }
}

// ---------------------------------------------------------------------------
// k_fc: out = combine(PO0,PO1) @ fcw^T + b. Combine fused into A-staging.
// 64x128 tile (grid 64x4 = 256 blocks), 4 waves 2x2 (32m x 64n).
// ---------------------------------------------------------------------------
__global__ __launch_bounds__(256, 2) void k_fc(
    const _Float16* __restrict__ ws, const float* __restrict__ fc_b,
    float* __restrict__ out)
{
  __shared__ _Float16 As[64 * 72];
  __shared__ _Float16 Bs[128 * 72];
  const int m0 = blockIdx.x * 64, n0 = blockIdx.y * 128;
  const int tid = threadIdx.x;
  const int lane = tid & 63, wv = tid >> 6;
  const int wm = wv >> 1, wn = wv & 1;
  const int lr = lane >> 4, lc = lane & 15;
  const int srowA = tid >> 2, c4 = (tid & 3) * 16;   // A: 64 rows x 64k
  const int srowB = tid >> 1, skB = (tid & 1) * 32;  // B: 128 rows x 64k
  const _Float16* PO0 = ws + OFF_V;
  const _Float16* PO1 = ws + OFF_AV;
  const float*    ML  = (const float*)ws;
  const _Float16* Bw  = ws + OFF_W + (size_t)4 * 512 * 512;

  const int am = m0 + srowA;
  const int ab = am >> 11, as = am & 2047;

  f32x4 acc[2][4];
#pragma unroll
  for (int i = 0; i < 2; ++i)
#pragma unroll
    for (int j = 0; j < 4; ++j) acc[i][j] = {0.f, 0.f, 0.f, 0.f};

  for (int kt = 0; kt < 8; ++kt) {
    { // stage A: combine split partials on load (head = kt)
      const int bhA = ab * NHD + kt;
      const int mlidx = bhA * S + as;
      const float mm0 = ML[mlidx], mm1 = ML[16 * 2048 + mlidx];
      const float ll0 = ML[65536 + mlidx], ll1 = ML[65536 + 16 * 2048 + mlidx];
      const float Mx = fmaxf(mm0, mm1);
      const float a0 = __expf(mm0 - Mx), a1 = __expf(mm1 - Mx);
      const float inv = 1.f / (ll0 * a0 + ll1 * a1);
      const float c0 = a0 * inv, c1 = a1 * inv;
      const size_t base = ((size_t)bhA * S + as) * DH + c4;
      _Float16* d = As + srowA * 72 + c4;
#pragma unroll
      for (int q = 0; q < 2; ++q) {
        const half8 p0 = *(const half8*)(PO0 + base + q * 8);
        const half8 p1 = *(const half8*)(PO1 + base + q * 8);
        half8 o;
#pragma unroll
        for (int i = 0; i < 8; ++i)
          o[i] = (_Float16)((float)p0[i] * c0 + (float)p1[i] * c1);
        *(half8*)(d + q * 8) = o;
      }
    }
    { // stage B (f16 fc weights)
      const _Float16* src = Bw + (size_t)(n0 + srowB) * 512 + kt * 64 + skB;
      _Float16* d = Bs + srowB * 72 + skB;
#pragma unroll
      for (int q = 0; q < 4; ++q) *(half8*)(d + q * 8) = *(const half8*)(src + q * 8);
    }
    __syncthreads();
#pragma unroll
    for (int ks = 0; ks < 2; ++ks) {
      half8 a[2], bfr[4];
#pragma unroll
      for (int f = 0; f < 2; ++f)
        a[f] = *(const half8*)(As + (wm * 32 + f * 16 + lc) * 72 + ks * 32 + lr * 8);
#pragma unroll
      for (int f = 0; f < 4; ++f)
        bfr[f] = *(const half8*)(Bs + (wn * 64 + f * 16 + lc) * 72 + ks * 32 + lr * 8);
#pragma unroll
      for (int fm = 0; fm < 2; ++fm)
#pragma unroll
        for (int fn = 0; fn < 4; ++fn)
          acc[fm][fn] = mfma16(a[fm], bfr[fn], acc[fm][fn]);
    }
    __syncthreads();
  }
#pragma unroll
  for (int fm = 0; fm < 2; ++fm)
#pragma unroll
    for (int fn = 0; fn < 4; ++fn)
#pragma unroll
      for (int r = 0; r < 4; ++r) {
        const int m = m0 + wm * 32 + fm * 16 + lr * 4 + r;
        const int n = n0 + wn * 64 + fn * 16 + lc;
        out[(size_t)m * 512 + n] = acc[fm][fn][r] + fc_b[n];
      }
}

// ---------------------------------------------------------------------------
extern "C" void kernel_launch(void* const* d_in, const int* in_sizes, int n_in,
                              void* d_out, int out_size, void* d_ws, size_t ws_size,
                              hipStream_t stream)
{
  (void)in_sizes; (void)n_in; (void)out_size; (void)ws_size;
  const float* q_in  = (const float*)d_in[0];
  const float* k_in  = (const float*)d_in[1];
  const float* v_in  = (const float*)d_in[2];
  const float* rel_r = (const float*)d_in[3];
  const float* rel_u = (const float*)d_in[4];
  const float* rel_v = (const float*)d_in[5];
  // d_in[6] = attn_mask: fixed causal triu(k=1) -- applied analytically in k_attn
  const float* Wq   = (const float*)d_in[7];
  const float* Wk   = (const float*)d_in[8];
  const float* Wv   = (const float*)d_in[9];
  const float* Wr   = (const float*)d_in[10];
  const float* fc_w = (const float*)d_in[11];
  const float* fc_b = (const float*)d_in[12];
  _Float16* ws = (_Float16*)d_ws;
  float* out = (float*)d_out;

  k_convert<<<1344, 256, 0, stream>>>(Wq, Wk, Wv, Wr, fc_w, ws);
  dim3 gp(32, 4, 4);
  k_proj<<<gp, 256, 0, stream>>>(q_in, k_in, v_in, rel_r, rel_u, rel_v, ws);
  k_vt<<<512, 256, 0, stream>>>(ws);
  k_attn<<<1024, 256, 0, stream>>>(ws);
  dim3 gf(64, 4);
  k_fc<<<gf, 256, 0, stream>>>(ws, fc_b, out);
}

// Round 6
// 108.611 us; speedup vs baseline: 1.2974x; 1.2974x over previous
//
#include <hip/hip_runtime.h>

typedef _Float16 half8 __attribute__((ext_vector_type(8)));
typedef float f32x4 __attribute__((ext_vector_type(4)));

// ---- problem constants ----
constexpr int S    = 2048;
constexpr int DMO  = 512;
constexpr int NHD  = 8;
constexpr int DH   = 64;
constexpr int BB   = 2;
constexpr int RRROWS = 64 + S + 64;   // 2176: 64 pad rows each side

// ---- workspace layout (in _Float16 elements) ----
constexpr size_t OFF_W  = 0;                                   // 5 * 512*512 (Wq,Wk,Wv,Wr,fcw as f16)
constexpr size_t OFF_QU = OFF_W  + (size_t)5*512*512;
constexpr size_t OFF_QV = OFF_QU + (size_t)BB*NHD*S*DH;
constexpr size_t OFF_K  = OFF_QV + (size_t)BB*NHD*S*DH;
constexpr size_t OFF_V  = OFF_K  + (size_t)BB*NHD*S*DH;
constexpr size_t OFF_VT = OFF_V  + (size_t)BB*NHD*S*DH;
constexpr size_t OFF_RR = OFF_VT + (size_t)BB*NHD*S*DH;
constexpr size_t OFF_AV = OFF_RR + (size_t)NHD*RRROWS*DH;
// Phase-based region reuse (each region is 2,097,152 halves = 16bh*2048*64):
//   attention phase:  OFF_V  -> PO[sp=0][bh][row][64]   (V dead after k_vt)
//                     OFF_AV -> PO[sp=1][bh][row][64]
//                     OFF_W[0:262144] (dead Wq f16) -> ML floats m[2][16][2048], l[2][16][2048]
//   fc: combine fused into A-staging (reads PO0/PO1/ML directly)
// NOTE: Qu/Qv are stored PRE-SCALED by 0.125 (folded softmax scale).

static __device__ __forceinline__ f32x4 mfma16(half8 a, half8 b, f32x4 c) {
  return __builtin_amdgcn_mfma_f32_16x16x32_f16(a, b, c, 0, 0, 0);
}

// ---------------------------------------------------------------------------
// k_convert: weights f32->f16 into ws; zero the RRrev pad rows.
// ---------------------------------------------------------------------------
__global__ __launch_bounds__(256) void k_convert(
    const float* __restrict__ Wq, const float* __restrict__ Wk,
    const float* __restrict__ Wv, const float* __restrict__ Wr,
    const float* __restrict__ fcw, _Float16* __restrict__ ws)
{
  const int idx = blockIdx.x * 256 + threadIdx.x;
  constexpr int WTOT = 5 * 512 * 512 / 4;      // 327680 float4 quads
  if (idx < WTOT) {
    const int i4  = idx * 4;
    const int w   = i4 >> 18;                  // which matrix (512*512 = 2^18)
    const int off = i4 & (512 * 512 - 1);
    const float* src = (w == 0) ? Wq : (w == 1) ? Wk : (w == 2) ? Wv : (w == 3) ? Wr : fcw;
    const float4 v = *(const float4*)(src + off);
    _Float16* dst = ws + OFF_W + (size_t)w * 512 * 512 + off;
    dst[0] = (_Float16)v.x; dst[1] = (_Float16)v.y;
    dst[2] = (_Float16)v.z; dst[3] = (_Float16)v.w;
  } else {
    const int p = idx - WTOT;                  // pad-zeroing of RRrev
    if (p < NHD * 128 * DH / 4) {
      const int e   = p * 4;
      const int h   = e >> 13;                 // 128*64 = 8192 per head
      const int rem = e & 8191;
      const int rr  = rem >> 6;                // 0..127
      const int col = rem & 63;
      const int row = (rr < 64) ? rr : (2048 + rr);   // rows [0,64) and [2112,2176)
      _Float16* dst = ws + OFF_RR + ((size_t)h * RRROWS + row) * DH + col;
      dst[0] = (_Float16)0.f; dst[1] = (_Float16)0.f;
      dst[2] = (_Float16)0.f; dst[3] = (_Float16)0.f;
    }
  }
}

// ---------------------------------------------------------------------------
// k_proj: C[m][n] = sum_k A[m][k] * W[n][k]; 128x128 tile, BK=64, 4 waves 2x2.
// z selects op: 0=Q(->Qu,Qv (val+rel)*0.125), 1=K, 2=V, 3=R(->RRrev reversed).
// Epilogue: acc -> LDS 128x140 f16 tile (aliases As/Bs) -> coalesced half8.
// ---------------------------------------------------------------------------
__global__ __launch_bounds__(256, 2) void k_proj(
    const float* __restrict__ q_in, const float* __restrict__ k_in,
    const float* __restrict__ v_in, const float* __restrict__ rel_r,
    const float* __restrict__ rel_u, const float* __restrict__ rel_v,
    _Float16* __restrict__ ws)
{
  __shared__ _Float16 SM[128 * 72 * 2];        // As | Bs; epilogue: Cs 128x140
  _Float16* As = SM;
  _Float16* Bs = SM + 128 * 72;
  const int op = blockIdx.z;
  const int M  = (op == 3) ? 2048 : 4096;
  const int m0 = blockIdx.x * 128, n0 = blockIdx.y * 128;
  if (m0 >= M) return;
  const float*    Ap = (op == 0) ? q_in : (op == 1) ? k_in : (op == 2) ? v_in : rel_r;
  const _Float16* Bw = ws + OFF_W + (size_t)op * 512 * 512;

  const int tid  = threadIdx.x;
  const int lane = tid & 63, wv = tid >> 6;
  const int wm = wv >> 1, wn = wv & 1;
  const int lr = lane >> 4, lc = lane & 15;
  const int srow = tid >> 1, sk = (tid & 1) * 32;

  f32x4 acc[4][4];
#pragma unroll
  for (int i = 0; i < 4; ++i)
#pragma unroll
    for (int j = 0; j < 4; ++j) acc[i][j] = {0.f, 0.f, 0.f, 0.f};

  for (int kt = 0; kt < 8; ++kt) {
    const int k0 = kt * 64;
    { // stage A (f32 -> f16)
      const float* src = Ap + (size_t)(m0 + srow) * 512 + k0 + sk;
      _Float16* d = As + srow * 72 + sk;
#pragma unroll
      for (int q = 0; q < 4; ++q) {
        const float4 a = ((const float4*)src)[2 * q];
        const float4 b = ((const float4*)src)[2 * q + 1];
        half8 h;
        h[0] = (_Float16)a.x; h[1] = (_Float16)a.y; h[2] = (_Float16)a.z; h[3] = (_Float16)a.w;
        h[4] = (_Float16)b.x; h[5] = (_Float16)b.y; h[6] = (_Float16)b.z; h[7] = (_Float16)b.w;
        *(half8*)(d + q * 8) = h;
      }
    }
    { // stage B (f16 weights)
      const _Float16* src = Bw + (size_t)(n0 + srow) * 512 + k0 + sk;
      _Float16* d = Bs + srow * 72 + sk;
#pragma unroll
      for (int q = 0; q < 4; ++q) *(half8*)(d + q * 8) = *(const half8*)(src + q * 8);
    }
    __syncthreads();
#pragma unroll
    for (int ks = 0; ks < 2; ++ks) {
      half8 a[4], b[4];
#pragma unroll
      for (int f = 0; f < 4; ++f)
        a[f] = *(const half8*)(As + (wm * 64 + f * 16 + lc) * 72 + ks * 32 + lr * 8);
#pragma unroll
      for (int f = 0; f < 4; ++f)
        b[f] = *(const half8*)(Bs + (wn * 64 + f * 16 + lc) * 72 + ks * 32 + lr * 8);
#pragma unroll
      for (int fm = 0; fm < 4; ++fm)
#pragma unroll
        for (int fn = 0; fn < 4; ++fn)
          acc[fm][fn] = mfma16(a[fm], b[fn], acc[fm][fn]);
    }
    __syncthreads();
  }

  // ---- epilogue: acc -> Cs (stride 140: lr-group banks {0,24,16,8}) ----
  _Float16* Cs = SM;
#pragma unroll
  for (int fm = 0; fm < 4; ++fm)
#pragma unroll
    for (int fn = 0; fn < 4; ++fn)
#pragma unroll
      for (int r = 0; r < 4; ++r)
        Cs[(wm * 64 + fm * 16 + lr * 4 + r) * 140 + wn * 64 + fn * 16 + lc] =
            (_Float16)acc[fm][fn][r];
  __syncthreads();

  const int row = tid >> 1;            // 0..127
  const int ch  = (tid & 1) * 64;      // 64-col half (head-aligned)
  const int m   = m0 + row;
  const int hh  = (n0 + ch) >> 6;
  if (op == 0) {
    const int b = m >> 11, s = m & 2047;
    const size_t base = ((size_t)(b * NHD + hh) * S + s) * DH;
#pragma unroll
    for (int q = 0; q < 8; ++q) {
      const half8 cv = *(const half8*)(Cs + row * 140 + ch + q * 8);
      half8 ou, ov;
#pragma unroll
      for (int i = 0; i < 8; ++i) {
        const int n = n0 + ch + q * 8 + i;
        const float v = (float)cv[i];
        ou[i] = (_Float16)((v + rel_u[n]) * 0.125f);
        ov[i] = (_Float16)((v + rel_v[n]) * 0.125f);
      }
      *(half8*)(ws + OFF_QU + base + q * 8) = ou;
      *(half8*)(ws + OFF_QV + base + q * 8) = ov;
    }
  } else if (op == 1 || op == 2) {
    const int b = m >> 11, s = m & 2047;
    _Float16* dst = ws + (op == 1 ? OFF_K : OFF_V) +
                    ((size_t)(b * NHD + hh) * S + s) * DH;
#pragma unroll
    for (int q = 0; q < 8; ++q)
      *(half8*)(dst + q * 8) = *(const half8*)(Cs + row * 140 + ch + q * 8);
  } else {
    const int rr = 2111 - m;            // RRrev[64 + (2047 - m)]
    _Float16* dst = ws + OFF_RR + ((size_t)hh * RRROWS + rr) * DH;
#pragma unroll
    for (int q = 0; q < 8; ++q)
      *(half8*)(dst + q * 8) = *(const half8*)(Cs + row * 140 + ch + q * 8);
  }
}

// ---------------------------------------------------------------------------
// k_vt: V[b,h,s,d] -> VT[b,h,d,s] via 64x64 LDS tile. (V region then dead.)
// ---------------------------------------------------------------------------
__global__ __launch_bounds__(256) void k_vt(_Float16* __restrict__ ws)
{
  __shared__ _Float16 t[64 * 72];
  const int bh = blockIdx.x >> 5, st = blockIdx.x & 31;
  const _Float16* V = ws + OFF_V + ((size_t)bh * S + st * 64) * DH;
  const int tid = threadIdx.x;
#pragma unroll
  for (int q = 0; q < 2; ++q) {
    const int c = tid + q * 256;               // 512 chunks of 8 halves
    *(half8*)(t + (c >> 3) * 72 + (c & 7) * 8) = *(const half8*)(V + c * 8);
  }
  __syncthreads();
  _Float16* VT = ws + OFF_VT + (size_t)bh * DH * S + st * 64;
#pragma unroll
  for (int q = 0; q < 2; ++q) {
    const int c = tid + q * 256;
    const int d = c >> 3, sp = (c & 7) * 8;
    half8 h;
#pragma unroll
    for (int i = 0; i < 8; ++i) h[i] = t[(sp + i) * 72 + d];
    *(half8*)(VT + (size_t)d * S + sp) = h;
  }
}

// ---------------------------------------------------------------------------
// k_attn: split-j flash attention, 3 blocks/CU (LDS 48.1KB) -- R4 structure
// (Vs staged in LDS; no long-live-range register V tiles -> no spills).
// 1024 blocks: qt=31-(bid>>5) heavy-first, bh=bid&15, sp=(bid>>4)&1.
// Ds: per-wave 80-col band [64][88]; Ps aliased into same buffer.
// Deferred softmax sum + defer-max THR=8. Qu/Qv pre-scaled by 0.125.
// ---------------------------------------------------------------------------
__global__ __launch_bounds__(256, 3) void k_attn(_Float16* __restrict__ ws)
{
  __shared__ _Float16 Ks[64 * 72];
  __shared__ _Float16 Vs[64 * 72];
  __shared__ _Float16 Rs[128 * 72];
  __shared__ _Float16 DsPs[64 * 88];           // Ds band + Ps (time-aliased)

  const int bid = blockIdx.x;
  const int qi  = bid >> 5;
  const int qt  = 31 - qi;                     // heavy tiles dispatched first
  const int bh  = bid & 15;
  const int sp  = (bid >> 4) & 1;
  const int i0  = qt * 64;
  const int h   = bh & 7;

  const int nt = qt + 1;                       // j-tiles in causal range
  const int nh = (nt + 1) >> 1;
  const int jb = sp ? nh : 0;
  const int je = sp ? nt : nh;

  const _Float16* Qu = ws + OFF_QU + (size_t)bh * S * DH;
  const _Float16* Qv = ws + OFF_QV + (size_t)bh * S * DH;
  const _Float16* Kg = ws + OFF_K  + (size_t)bh * S * DH;
  const _Float16* VT = ws + OFF_VT + (size_t)bh * DH * S;
  const _Float16* RR = ws + OFF_RR + (size_t)h * RRROWS * DH;
  _Float16* PO = ws + (sp ? OFF_AV : OFF_V);   // [bh][row][64] per split
  float*    ML = (float*)ws;                   // m: [sp][bh][2048]; l at +65536

  const int tid = threadIdx.x, lane = tid & 63, wv = tid >> 6;
  const int lr = lane >> 4, lc = lane & 15;

  half8 qu[2], qv[2];
  {
    const size_t ro = (size_t)(i0 + wv * 16 + lc) * DH + lr * 8;
    qu[0] = *(const half8*)(Qu + ro); qu[1] = *(const half8*)(Qu + ro + 32);
    qv[0] = *(const half8*)(Qv + ro); qv[1] = *(const half8*)(Qv + ro + 32);
  }

  f32x4 oacc[4];
#pragma unroll
  for (int i = 0; i < 4; ++i) oacc[i] = {0.f, 0.f, 0.f, 0.f};
  float mrow[4] = {-1e30f, -1e30f, -1e30f, -1e30f};
  float lrow[4] = {0.f, 0.f, 0.f, 0.f};        // per-lane partial sums

  for (int jt = jb; jt < je; ++jt) {
    const int j0 = jt * 64;
    // ---- stage K tile, VT tile, RR window ----
    {
      const _Float16* src = Kg + (size_t)j0 * DH;
#pragma unroll
      for (int q = 0; q < 2; ++q) {
        const int c = tid + q * 256;
        *(half8*)(Ks + (c >> 3) * 72 + (c & 7) * 8) = *(const half8*)(src + c * 8);
      }
#pragma unroll
      for (int q = 0; q < 2; ++q) {
        const int c = tid + q * 256;
        const int d = c >> 3, cp = (c & 7) * 8;
        *(half8*)(Vs + d * 72 + cp) = *(const half8*)(VT + (size_t)d * S + j0 + cp);
      }
      const int r0 = i0 - j0 + 1;
#pragma unroll
      for (int q = 0; q < 4; ++q) {
        const int c = tid + q * 256;
        const int row = c >> 3, cp = (c & 7) * 8;
        *(half8*)(Rs + row * 72 + cp) = *(const half8*)(RR + (size_t)(r0 + row) * DH + cp);
      }
    }
    __syncthreads();

    // ---- D band = Qv @ RRwin^T, cols [wv*16, wv*16+80) -> band store ----
    {
      f32x4 dacc[5];
#pragma unroll
      for (int i = 0; i < 5; ++i) dacc[i] = {0.f, 0.f, 0.f, 0.f};
#pragma unroll
      for (int cf = 0; cf < 5; ++cf)
#pragma unroll
        for (int ks = 0; ks < 2; ++ks) {
          const half8 rb = *(const half8*)(Rs + ((wv + cf) * 16 + lc) * 72 + ks * 32 + lr * 8);
          dacc[cf] = mfma16(qv[ks], rb, dacc[cf]);
        }
#pragma unroll
      for (int cf = 0; cf < 5; ++cf)
#pragma unroll
        for (int r = 0; r < 4; ++r)
          DsPs[(wv * 16 + lr * 4 + r) * 88 + cf * 16 + lc] = (_Float16)dacc[cf][r];
    }

    // ---- AC = Qu @ K^T ----
    f32x4 sacc[4];
#pragma unroll
    for (int i = 0; i < 4; ++i) sacc[i] = {0.f, 0.f, 0.f, 0.f};
#pragma unroll
    for (int jf = 0; jf < 4; ++jf)
#pragma unroll
      for (int ks = 0; ks < 2; ++ks) {
        const half8 kb = *(const half8*)(Ks + (jf * 16 + lc) * 72 + ks * 32 + lr * 8);
        sacc[jf] = mfma16(qu[ks], kb, sacc[jf]);
      }

    // ---- scores (band-read D; pre-scaled) + online softmax ----
    const bool diag = (j0 == i0);
    float sv[4][4];
    float rmax[4] = {-1e30f, -1e30f, -1e30f, -1e30f};
#pragma unroll
    for (int jf = 0; jf < 4; ++jf)
#pragma unroll
      for (int r = 0; r < 4; ++r) {
        const int rr4 = lr * 4 + r;            // row within wave slice
        const int ii  = wv * 16 + rr4;
        const int jj  = jf * 16 + lc;
        float x = sacc[jf][r] + (float)DsPs[ii * 88 + rr4 + 63 - jj];
        if (diag && (jj > ii)) x = -1e30f;     // causal mask, diag tile only
        sv[jf][r] = x;
        rmax[r] = fmaxf(rmax[r], x);
      }
#pragma unroll
    for (int r = 0; r < 4; ++r)
#pragma unroll
      for (int d = 1; d < 16; d <<= 1)
        rmax[r] = fmaxf(rmax[r], __shfl_xor(rmax[r], d));

    // defer-max: only rescale when max grew by > 8
    bool ok = true;
#pragma unroll
    for (int r = 0; r < 4; ++r) ok = ok && (rmax[r] <= mrow[r] + 8.f);
    if (!__all((int)ok)) {
#pragma unroll
      for (int r = 0; r < 4; ++r) {
        const float mn = fmaxf(mrow[r], rmax[r]);
        const float al = __expf(mrow[r] - mn);
        mrow[r] = mn;
        lrow[r] *= al;
#pragma unroll
        for (int nf = 0; nf < 4; ++nf) oacc[nf][r] *= al;
      }
    }

    // ---- P = exp(S - m); per-lane partial sums; store to Ps (aliased) ----
#pragma unroll
    for (int jf = 0; jf < 4; ++jf)
#pragma unroll
      for (int r = 0; r < 4; ++r) {
        const int ii = wv * 16 + lr * 4 + r;
        const int jj = jf * 16 + lc;
        const float p = __expf(sv[jf][r] - mrow[r]);
        lrow[r] += p;
        DsPs[ii * 88 + jj] = (_Float16)p;
      }

    // ---- O += P @ V ----
#pragma unroll
    for (int ks = 0; ks < 2; ++ks) {
      const half8 pa = *(const half8*)(DsPs + (wv * 16 + lc) * 88 + ks * 32 + lr * 8);
#pragma unroll
      for (int nf = 0; nf < 4; ++nf) {
        const half8 vb = *(const half8*)(Vs + (nf * 16 + lc) * 72 + ks * 32 + lr * 8);
        oacc[nf] = mfma16(pa, vb, oacc[nf]);
      }
    }
    __syncthreads();
  }

  // ---- epilogue: reduce lrow, write unnormalized partials ----
#pragma unroll
  for (int r = 0; r < 4; ++r)
#pragma unroll
    for (int d = 1; d < 16; d <<= 1)
      lrow[r] += __shfl_xor(lrow[r], d);

#pragma unroll
  for (int nf = 0; nf < 4; ++nf)
#pragma unroll
    for (int r = 0; r < 4; ++r) {
      const int row = i0 + wv * 16 + lr * 4 + r;
      PO[((size_t)bh * S + row) * DH + nf * 16 + lc] = (_Float16)oacc[nf][r];
    }
  if (lc == 0) {
#pragma unroll
    for (int r = 0; r < 4; ++r) {
      const int row = i0 + wv * 16 + lr * 4 + r;
      const int idx = (sp * 16 + bh) * S + row;
      ML[idx]         = mrow[r];
      ML[65536 + idx] = lrow[r];
    }
  }
}

// ---------------------------------------------------------------------------
// k_fc: out = combine(PO0,PO1) @ fcw^T + b. Combine fused into A-staging.
// 64x128 tile (grid 64x4 = 256 blocks), 4 waves 2x2 (32m x 64n).
// ---------------------------------------------------------------------------
__global__ __launch_bounds__(256, 2) void k_fc(
    const _Float16* __restrict__ ws, const float* __restrict__ fc_b,
    float* __restrict__ out)
{
  __shared__ _Float16 As[64 * 72];
  __shared__ _Float16 Bs[128 * 72];
  const int m0 = blockIdx.x * 64, n0 = blockIdx.y * 128;
  const int tid = threadIdx.x;
  const int lane = tid & 63, wv = tid >> 6;
  const int wm = wv >> 1, wn = wv & 1;
  const int lr = lane >> 4, lc = lane & 15;
  const int srowA = tid >> 2, c4 = (tid & 3) * 16;   // A: 64 rows x 64k
  const int srowB = tid >> 1, skB = (tid & 1) * 32;  // B: 128 rows x 64k
  const _Float16* PO0 = ws + OFF_V;
  const _Float16* PO1 = ws + OFF_AV;
  const float*    ML  = (const float*)ws;
  const _Float16* Bw  = ws + OFF_W + (size_t)4 * 512 * 512;

  const int am = m0 + srowA;
  const int ab = am >> 11, as = am & 2047;

  f32x4 acc[2][4];
#pragma unroll
  for (int i = 0; i < 2; ++i)
#pragma unroll
    for (int j = 0; j < 4; ++j) acc[i][j] = {0.f, 0.f, 0.f, 0.f};

  for (int kt = 0; kt < 8; ++kt) {
    { // stage A: combine split partials on load (head = kt)
      const int bhA = ab * NHD + kt;
      const int mlidx = bhA * S + as;
      const float mm0 = ML[mlidx], mm1 = ML[16 * 2048 + mlidx];
      const float ll0 = ML[65536 + mlidx], ll1 = ML[65536 + 16 * 2048 + mlidx];
      const float Mx = fmaxf(mm0, mm1);
      const float a0 = __expf(mm0 - Mx), a1 = __expf(mm1 - Mx);
      const float inv = 1.f / (ll0 * a0 + ll1 * a1);
      const float c0 = a0 * inv, c1 = a1 * inv;
      const size_t base = ((size_t)bhA * S + as) * DH + c4;
      _Float16* d = As + srowA * 72 + c4;
#pragma unroll
      for (int q = 0; q < 2; ++q) {
        const half8 p0 = *(const half8*)(PO0 + base + q * 8);
        const half8 p1 = *(const half8*)(PO1 + base + q * 8);
        half8 o;
#pragma unroll
        for (int i = 0; i < 8; ++i)
          o[i] = (_Float16)((float)p0[i] * c0 + (float)p1[i] * c1);
        *(half8*)(d + q * 8) = o;
      }
    }
    { // stage B (f16 fc weights)
      const _Float16* src = Bw + (size_t)(n0 + srowB) * 512 + kt * 64 + skB;
      _Float16* d = Bs + srowB * 72 + skB;
#pragma unroll
      for (int q = 0; q < 4; ++q) *(half8*)(d + q * 8) = *(const half8*)(src + q * 8);
    }
    __syncthreads();
#pragma unroll
    for (int ks = 0; ks < 2; ++ks) {
      half8 a[2], bfr[4];
#pragma unroll
      for (int f = 0; f < 2; ++f)
        a[f] = *(const half8*)(As + (wm * 32 + f * 16 + lc) * 72 + ks * 32 + lr * 8);
#pragma unroll
      for (int f = 0; f < 4; ++f)
        bfr[f] = *(const half8*)(Bs + (wn * 64 + f * 16 + lc) * 72 + ks * 32 + lr * 8);
#pragma unroll
      for (int fm = 0; fm < 2; ++fm)
#pragma unroll
        for (int fn = 0; fn < 4; ++fn)
          acc[fm][fn] = mfma16(a[fm], bfr[fn], acc[fm][fn]);
    }
    __syncthreads();
  }
#pragma unroll
  for (int fm = 0; fm < 2; ++fm)
#pragma unroll
    for (int fn = 0; fn < 4; ++fn)
#pragma unroll
      for (int r = 0; r < 4; ++r) {
        const int m = m0 + wm * 32 + fm * 16 + lr * 4 + r;
        const int n = n0 + wn * 64 + fn * 16 + lc;
        out[(size_t)m * 512 + n] = acc[fm][fn][r] + fc_b[n];
      }
}

// ---------------------------------------------------------------------------
extern "C" void kernel_launch(void* const* d_in, const int* in_sizes, int n_in,
                              void* d_out, int out_size, void* d_ws, size_t ws_size,
                              hipStream_t stream)
{
  (void)in_sizes; (void)n_in; (void)out_size; (void)ws_size;
  const float* q_in  = (const float*)d_in[0];
  const float* k_in  = (const float*)d_in[1];
  const float* v_in  = (const float*)d_in[2];
  const float* rel_r = (const float*)d_in[3];
  const float* rel_u = (const float*)d_in[4];
  const float* rel_v = (const float*)d_in[5];
  // d_in[6] = attn_mask: fixed causal triu(k=1) -- applied analytically in k_attn
  const float* Wq   = (const float*)d_in[7];
  const float* Wk   = (const float*)d_in[8];
  const float* Wv   = (const float*)d_in[9];
  const float* Wr   = (const float*)d_in[10];
  const float* fc_w = (const float*)d_in[11];
  const float* fc_b = (const float*)d_in[12];
  _Float16* ws = (_Float16*)d_ws;
  float* out = (float*)d_out;

  k_convert<<<1344, 256, 0, stream>>>(Wq, Wk, Wv, Wr, fc_w, ws);
  dim3 gp(32, 4, 4);
  k_proj<<<gp, 256, 0, stream>>>(q_in, k_in, v_in, rel_r, rel_u, rel_v, ws);
  k_vt<<<512, 256, 0, stream>>>(ws);
  k_attn<<<1024, 256, 0, stream>>>(ws);
  dim3 gf(64, 4);
  k_fc<<<gf, 256, 0, stream>>>(ws, fc_b, out);
}